// Round 15
// baseline (89.624 us; speedup 1.0000x reference)
//
#include <hip/hip_runtime.h>
#include <cstddef>

using bf16x8  = __attribute__((ext_vector_type(8))) short;
using f32x4   = __attribute__((ext_vector_type(4))) float;
using ushort8 = __attribute__((ext_vector_type(8))) unsigned short;

#define GLL16(gp, lp) __builtin_amdgcn_global_load_lds( \
    (const __attribute__((address_space(1))) unsigned int*)(const void*)(gp), \
    (__attribute__((address_space(3))) unsigned int*)(void*)(lp), 16, 0, 0)

__device__ __forceinline__ float exp2_f(float x){ float r; asm("v_exp_f32 %0, %1" : "=v"(r) : "v"(x)); return r; }
__device__ __forceinline__ float rcp_f (float x){ float r; asm("v_rcp_f32 %0, %1" : "=v"(r) : "v"(x)); return r; }
__device__ __forceinline__ unsigned pk2(float lo, float hi){
  unsigned r; asm("v_cvt_pk_bf16_f32 %0, %1, %2" : "=v"(r) : "v"(lo), "v"(hi)); return r;
}
__device__ __forceinline__ unsigned short f2bf(float f){
  unsigned int u = __float_as_uint(f);
  u = u + 0x7FFFu + ((u >> 16) & 1u);
  return (unsigned short)(u >> 16);
}

// problem sizes: B=8 Q=16 KV=2048 NQ=NK=NV=H=512
#define KEYS_N   8388608
#define QG_BLOCKS 16              // qgemm blocks FIRST (start at t=0, hide under convert)
#define CONV_BLOCKS 4224          // 4096 keys + 128 wk
#define SCALE_2LOG2E 2.885390081777927f   // 2*log2(e): exp2(x*S) = exp(2x)

// workspace layout (bytes); total = 56,360,960
#define OFF_KEYS_BF   0u          // 16384x512 bf16
#define OFF_WK_BF     16777216u   // 512x512 bf16
#define OFF_EQB       17301504u   // 128x512 f32: exp2(S*q_part)
#define OFF_EKB       17563648u   // 16384x512 f32: exp2(S*(k_part+bias))
#define OFF_EPART     51118080u   // 4 x [8*2048*16] f32 partial logits
#define OFF_SC        55312384u   // 8x2048x16 f32 scores

// ---------------- K1: q-GEMM (blocks 0..15) ∥ convert (blocks 16..4239) ---
__global__ __launch_bounds__(256) void k_convert(
    const float* __restrict__ keys, const float* __restrict__ W,
    const float* __restrict__ query,
    unsigned short* __restrict__ keys_bf, unsigned short* __restrict__ wk_bf,
    float* __restrict__ eqb)
{
  __shared__ short qg[128*32 + 32*32];     // 10 KB (qgemm branch only)
  if (blockIdx.x < QG_BLOCKS) {
    const int n0 = blockIdx.x * 32;
    const int tid = threadIdx.x;
    const int l = tid & 63, w = tid >> 6;
    short* A  = qg;                 // [128][32] swizzled
    short* Bs = qg + 4096;          // [32][32] swizzled
    const int sub = tid >> 3;       // 0..31
    const int c4  = (tid & 7) * 4;  // col within 32
    const int wm = w & 1, wn = w >> 1;
    const int fr = l & 15, fg = l >> 4;

    f32x4 acc[4];
    #pragma unroll
    for (int i = 0; i < 4; ++i) acc[i] = (f32x4){0.f,0.f,0.f,0.f};

    float4 a4[4], b4, a4n[4], b4n;
    #pragma unroll
    for (int m = 0; m < 4; ++m)
      a4[m] = *(const float4*)(query + (size_t)(m * 32 + sub) * 512 + c4);
    b4 = *(const float4*)(W + (size_t)(n0 + sub) * 1024 + c4);

    for (int kt = 0; kt < 16; ++kt) {
      if (kt < 15) {                 // issue next-kt loads early (overlap)
        const int k0 = (kt + 1) * 32;
        #pragma unroll
        for (int m = 0; m < 4; ++m)
          a4n[m] = *(const float4*)(query + (size_t)(m * 32 + sub) * 512 + k0 + c4);
        b4n = *(const float4*)(W + (size_t)(n0 + sub) * 1024 + k0 + c4);
      }
      __syncthreads();              // prior mfma reads done before overwrite
      #pragma unroll
      for (int m = 0; m < 4; ++m) {
        const int row = m * 32 + sub;
        const int o = row * 32 + (((c4 >> 3) ^ ((row >> 1) & 3)) << 3) + (c4 & 7);
        *(uint2*)&A[o] = make_uint2(pk2(a4[m].x, a4[m].y), pk2(a4[m].z, a4[m].w));
      }
      {
        const int o = sub * 32 + (((c4 >> 3) ^ ((sub >> 1) & 3)) << 3) + (c4 & 7);
        *(uint2*)&Bs[o] = make_uint2(pk2(b4.x, b4.y), pk2(b4.z, b4.w));
      }
      __syncthreads();
      bf16x8 af[4], bfv;
      #pragma unroll
      for (int i = 0; i < 4; ++i) {
        const int ar = wm*64 + i*16 + fr;
        af[i] = *(const bf16x8*)&A[ar*32 + ((fg ^ ((ar>>1)&3)) << 3)];
      }
      const int br = wn*16 + fr;
      bfv = *(const bf16x8*)&Bs[br*32 + ((fg ^ ((br>>1)&3)) << 3)];
      #pragma unroll
      for (int i = 0; i < 4; ++i)
        acc[i] = __builtin_amdgcn_mfma_f32_16x16x32_bf16(af[i], bfv, acc[i], 0, 0, 0);
      if (kt < 15) {
        #pragma unroll
        for (int m = 0; m < 4; ++m) a4[m] = a4n[m];
        b4 = b4n;
      }
    }
    const int gh = n0 + wn*16 + fr;
    #pragma unroll
    for (int i = 0; i < 4; ++i)
      #pragma unroll
      for (int r = 0; r < 4; ++r) {
        const int gm = wm*64 + i*16 + fg*4 + r;
        eqb[gm * 512 + gh] = exp2_f(acc[i][r] * SCALE_2LOG2E);
      }
    return;
  }
  // ---- convert path
  int idx = ((blockIdx.x - QG_BLOCKS) * 256 + threadIdx.x) * 8;
  const float* src;
  unsigned short* dst;
  if (idx < KEYS_N) { src = keys + idx; dst = keys_bf + idx; }
  else {
    int e = idx - KEYS_N;                    // wk[h][c]
    src = W + (size_t)(e >> 9) * 1024 + 512 + (e & 511);
    dst = wk_bf + e;
  }
  float4 a = *(const float4*)src;
  float4 b = *(const float4*)(src + 4);
  ushort8 o;
  o[0]=f2bf(a.x); o[1]=f2bf(a.y); o[2]=f2bf(a.z); o[3]=f2bf(a.w);
  o[4]=f2bf(b.x); o[5]=f2bf(b.y); o[6]=f2bf(b.z); o[7]=f2bf(b.w);
  *(ushort8*)dst = o;
}

// ---------------- K2: k-GEMM -> ekb = exp2(S*(keys·Wk^T + bias)) ----------
// r12's counted-vmcnt dbuf pipeline; epilogue stores f32 to global.
struct GemmSM { short A[2][8192]; short B[2][8192]; };   // 64 KB

__global__ __launch_bounds__(256, 2) void k_gemm(
    const unsigned short* __restrict__ keys_bf, const unsigned short* __restrict__ wk_bf,
    const float* __restrict__ w_bias, float* __restrict__ ekb)
{
  __shared__ GemmSM sm;
  const int tid = threadIdx.x;
  const int l = tid & 63, w = tid >> 6;
  const int by = blockIdx.x;              // 0..127 m-tile (128 k-rows)
  const int hc = blockIdx.y;              // 0..3 h-chunk
  const int h0 = hc * 128;

  const unsigned short* Aptr = keys_bf + (size_t)by * 128 * 512;
  const unsigned short* Bptr = wk_bf + (size_t)h0 * 512;

  const int srow = w * 32 + (l >> 3);
  const int scol = ((l & 7) ^ (l >> 3)) * 8;
  const int wm = w >> 1, wn = w & 1;
  const int fr = l & 15, fg = l >> 4;
  const int axk = fr & 7;

  f32x4 acc[4][4];
  #pragma unroll
  for (int i = 0; i < 4; ++i)
    #pragma unroll
    for (int j = 0; j < 4; ++j) acc[i][j] = (f32x4){0.f,0.f,0.f,0.f};

  auto stage = [&](int buf, int kt) {
    const int k0 = kt * 64;
    #pragma unroll
    for (int r = 0; r < 4; ++r) {
      GLL16(Aptr + (srow + r * 8) * 512 + k0 + scol, &sm.A[buf][w * 2048 + r * 512]);
      GLL16(Bptr + (srow + r * 8) * 512 + k0 + scol, &sm.B[buf][w * 2048 + r * 512]);
    }
  };
  auto compute = [&](int buf) {
    #pragma unroll
    for (int ks = 0; ks < 2; ++ks) {
      bf16x8 af[4], bfv[4];
      #pragma unroll
      for (int i = 0; i < 4; ++i) {
        af[i]  = *(const bf16x8*)&sm.A[buf][(wm*64 + i*16 + fr) * 64 + ((ks*4 + fg) ^ axk) * 8];
        bfv[i] = *(const bf16x8*)&sm.B[buf][(wn*64 + i*16 + fr) * 64 + ((ks*4 + fg) ^ axk) * 8];
      }
      #pragma unroll
      for (int i = 0; i < 4; ++i)
        #pragma unroll
        for (int j = 0; j < 4; ++j)
          acc[i][j] = __builtin_amdgcn_mfma_f32_16x16x32_bf16(af[i], bfv[j], acc[i][j], 0, 0, 0);
    }
  };

  stage(0, 0);
  #pragma unroll 1
  for (int kt = 0; kt < 8; ++kt) {
    if (kt < 7) {
      stage((kt + 1) & 1, kt + 1);     // prefetch stays in flight across barrier
      asm volatile("s_waitcnt vmcnt(8)" ::: "memory");
    } else {
      asm volatile("s_waitcnt vmcnt(0)" ::: "memory");
    }
    __builtin_amdgcn_sched_barrier(0);
    __builtin_amdgcn_s_barrier();        // buf[kt&1] staged for ALL waves
    __builtin_amdgcn_sched_barrier(0);
    compute(kt & 1);
    asm volatile("s_waitcnt lgkmcnt(0)" ::: "memory");
    __builtin_amdgcn_sched_barrier(0);
    __builtin_amdgcn_s_barrier();        // all reads of buf[kt&1] done
    __builtin_amdgcn_sched_barrier(0);
  }

  // epilogue: ekb[row_global][h] = exp2(S*(acc + bias))
  #pragma unroll
  for (int j = 0; j < 4; ++j) {
    const int col = wn*64 + j*16 + fr;
    const float bias = w_bias[h0 + col];
    #pragma unroll
    for (int i = 0; i < 4; ++i)
      #pragma unroll
      for (int r = 0; r < 4; ++r) {
        const int row = wm*64 + i*16 + fg*4 + r;
        ekb[(size_t)(by * 128 + row) * 512 + h0 + col] =
            exp2_f((acc[i][j][r] + bias) * SCALE_2LOG2E);
      }
  }
}

// ---------------- K3: energy (standalone, high-occupancy) -----------------
// block (by2, hc): 32 k-rows x 128 h x 16 q. LDS: ek tile 16KB + vv 512B.
// lane (ql = (l&63)>>2, g = l&3): owns ONE q and the g-th 4-col slice of
// each 16-col group; eq[32] in regs. All LDS reads are 4-address x 16-lane
// broadcast (conflict-free). 6 blocks/CU -> 6 waves/SIMD hides rcp/LDS lat.
__global__ __launch_bounds__(256, 6) void k_energy(
    const float* __restrict__ ekb, const float* __restrict__ eqb,
    const float* __restrict__ vw, float* __restrict__ e_part)
{
  __shared__ float ekt[32 * 128];   // 16 KB
  __shared__ float vvs[128];        // 512 B
  const int tid = threadIdx.x;
  const int l = tid & 63, w = tid >> 6;
  const int by2 = blockIdx.x;       // 0..511 (32-row tiles over 16384 rows)
  const int hc = blockIdx.y;        // 0..3
  const int h0 = hc * 128;
  const int b = by2 >> 6;           // 64 tiles per batch

  // stage ek tile [32][128] f32 via GLL16 (4 rounds; dest wave-uniform)
  {
    const float* src = ekb + (size_t)by2 * 32 * 512 + h0;
    #pragma unroll
    for (int m = 0; m < 4; ++m) {
      const int e4b = m * 256 + w * 64;          // wave-uniform 16B-unit base
      const int e4 = e4b + l;                    // per-lane unit
      const int row = e4 >> 5, c4 = (e4 & 31) * 4;
      GLL16(src + (size_t)row * 512 + c4, &ekt[e4b * 4]);
    }
  }
  if (tid < 32) {
    const float4 v4 = *(const float4*)(vw + h0 + tid * 4);
    vvs[tid*4+0] = -2.f*v4.x; vvs[tid*4+1] = -2.f*v4.y;
    vvs[tid*4+2] = -2.f*v4.z; vvs[tid*4+3] = -2.f*v4.w;
  }

  // eq[32] in registers: lane's q-row, its 8 4-col slices
  const int ql = l >> 2, g = l & 3;
  float eq[32];
  #pragma unroll
  for (int s = 0; s < 4; ++s)
    #pragma unroll
    for (int hf = 0; hf < 2; ++hf) {
      const float4 e4 = *(const float4*)(eqb + (size_t)(b * 16 + ql) * 512
                                         + h0 + s*32 + hf*16 + g*4);
      const int o = s*8 + hf*4;
      eq[o+0]=e4.x; eq[o+1]=e4.y; eq[o+2]=e4.z; eq[o+3]=e4.w;
    }
  __syncthreads();

  // wave w: rows w*8 .. w*8+8
  #pragma unroll 2
  for (int rr = 0; rr < 8; ++rr) {
    const int row = w * 8 + rr;
    float a = 0.f;
    #pragma unroll
    for (int s = 0; s < 4; ++s)
      #pragma unroll
      for (int hf = 0; hf < 2; ++hf) {
        const int c = s*32 + hf*16 + g*4;
        const float4 E = *(const float4*)&ekt[row * 128 + c];
        const float4 V = *(const float4*)&vvs[c];
        const int o = s*8 + hf*4;
        a = fmaf(V.x, rcp_f(fmaf(E.x, eq[o+0], 1.f)), a);
        a = fmaf(V.y, rcp_f(fmaf(E.y, eq[o+1], 1.f)), a);
        a = fmaf(V.z, rcp_f(fmaf(E.z, eq[o+2], 1.f)), a);
        a = fmaf(V.w, rcp_f(fmaf(E.w, eq[o+3], 1.f)), a);
      }
    a += __shfl_xor(a, 1, 64);          // reduce over g
    a += __shfl_xor(a, 2, 64);
    if (g == 0)
      e_part[(size_t)hc * 262144 + ((size_t)(by2 * 32 + row)) * 16 + ql] = a;
  }
}

// ---------------- K4: softmax over k: sum 4 partials, normalize -----------
__global__ __launch_bounds__(256) void k_softmax(
    const float* __restrict__ e_part, float* __restrict__ sc)
{
  const int b = blockIdx.x >> 4, q = blockIdx.x & 15;
  const int base = b * 32768 + q;           // stride 16 over k
  const int tid = threadIdx.x;
  __shared__ float redm[4], reds[4];

  float vals[8];
  float mx = -1e30f;
  #pragma unroll
  for (int i = 0; i < 8; ++i) {
    const int x = base + (tid + i * 256) * 16;
    vals[i] = (e_part[x] + e_part[x + 262144]) + (e_part[x + 524288] + e_part[x + 786432]);
    mx = fmaxf(mx, vals[i]);
  }
  #pragma unroll
  for (int msk = 1; msk < 64; msk <<= 1) mx = fmaxf(mx, __shfl_xor(mx, msk, 64));
  if ((tid & 63) == 0) redm[tid >> 6] = mx;
  __syncthreads();
  mx = fmaxf(fmaxf(redm[0], redm[1]), fmaxf(redm[2], redm[3]));

  float ex[8], sum = 0.f;
  #pragma unroll
  for (int i = 0; i < 8; ++i) { ex[i] = __expf(vals[i] - mx); sum += ex[i]; }
  #pragma unroll
  for (int msk = 1; msk < 64; msk <<= 1) sum += __shfl_xor(sum, msk, 64);
  if ((tid & 63) == 0) reds[tid >> 6] = sum;
  __syncthreads();
  sum = reds[0] + reds[1] + reds[2] + reds[3];
  const float r = 1.f / sum;
  #pragma unroll
  for (int i = 0; i < 8; ++i) sc[base + (tid + i * 256) * 16] = ex[i] * r;
}

// ---------------- K5: single-pass PV -> out, 256 blocks x 512 thr ---------
__global__ __launch_bounds__(512) void k_pv(
    const float* __restrict__ values, const float* __restrict__ sc,
    float* __restrict__ out)
{
  __shared__ float lds[128 * 20];            // 10 KB (stride-20: 2-way max)
  const int tid = threadIdx.x;
  const int nc = blockIdx.x & 31, b = blockIdx.x >> 5;
  const int n = tid & 15, kg = tid >> 4;     // 32 kg x 16 n
  const int l = tid & 63, w = tid >> 6;      // 8 waves
  const int n0 = nc * 16;

  float acc[16];
  #pragma unroll
  for (int q = 0; q < 16; ++q) acc[q] = 0.f;

  for (int kc = 0; kc < 16; ++kc) {
    __syncthreads();
    {
      const float* ssrc = sc + (size_t)(b * 2048 + kc * 128) * 16;
      const int row = tid >> 2, c4 = (tid & 3) * 4;
      *(float4*)&lds[row * 20 + c4] = *(const float4*)&ssrc[row * 16 + c4];
    }
    __syncthreads();
    const float* vb = values + ((size_t)(b * 2048 + kc * 128 + kg * 4)) * 512 + n0 + n;
    #pragma unroll
    for (int k2 = 0; k2 < 4; ++k2) {
      const float v = vb[(size_t)k2 * 512];
      const float* sr = &lds[(kg * 4 + k2) * 20];
      #pragma unroll
      for (int qq = 0; qq < 4; ++qq) {
        const float4 s4 = *(const float4*)&sr[qq * 4];
        acc[qq*4+0] = fmaf(v, s4.x, acc[qq*4+0]);
        acc[qq*4+1] = fmaf(v, s4.y, acc[qq*4+1]);
        acc[qq*4+2] = fmaf(v, s4.z, acc[qq*4+2]);
        acc[qq*4+3] = fmaf(v, s4.w, acc[qq*4+3]);
      }
    }
  }
  // within-wave reduce (lanes l, l^16, l^32 share n)
  #pragma unroll
  for (int q = 0; q < 16; ++q) {
    acc[q] += __shfl_xor(acc[q], 16, 64);
    acc[q] += __shfl_xor(acc[q], 32, 64);
  }
  __syncthreads();
  if (l < 16) {
    #pragma unroll
    for (int q = 0; q < 16; ++q) lds[w * 256 + q * 16 + l] = acc[q];
  }
  __syncthreads();
  if (tid < 256) {
    const int q = tid >> 4, nn = tid & 15;
    float s = 0.f;
    #pragma unroll
    for (int w2 = 0; w2 < 8; ++w2) s += lds[w2 * 256 + q * 16 + nn];
    out[((size_t)(b * 16 + q)) * 512 + n0 + nn] = s;
  }
}

extern "C" void kernel_launch(void* const* d_in, const int* in_sizes, int n_in,
                              void* d_out, int out_size, void* d_ws, size_t ws_size,
                              hipStream_t stream)
{
  const float* query  = (const float*)d_in[0];
  const float* keys   = (const float*)d_in[1];
  const float* values = (const float*)d_in[2];
  const float* W      = (const float*)d_in[3];
  const float* w_bias = (const float*)d_in[4];
  const float* vw     = (const float*)d_in[5];
  // d_in[6] (v_bias) + sum_h v_h are (k)-constant logit shifts -> softmax-invariant.

  char* ws = (char*)d_ws;
  unsigned short* keys_bf = (unsigned short*)(ws + OFF_KEYS_BF);
  unsigned short* wk_bf   = (unsigned short*)(ws + OFF_WK_BF);
  float* eqb    = (float*)(ws + OFF_EQB);
  float* ekb    = (float*)(ws + OFF_EKB);
  float* e_part = (float*)(ws + OFF_EPART);
  float* sc     = (float*)(ws + OFF_SC);

  hipLaunchKernelGGL(k_convert, dim3(QG_BLOCKS + CONV_BLOCKS), dim3(256), 0, stream,
                     keys, W, query, keys_bf, wk_bf, eqb);
  hipLaunchKernelGGL(k_gemm, dim3(128, 4), dim3(256), 0, stream,
                     keys_bf, wk_bf, w_bias, ekb);
  hipLaunchKernelGGL(k_energy, dim3(512, 4), dim3(256), 0, stream,
                     ekb, eqb, vw, e_part);
  hipLaunchKernelGGL(k_softmax, dim3(128), dim3(256), 0, stream, e_part, sc);
  hipLaunchKernelGGL(k_pv, dim3(256), dim3(512), 0, stream, values, sc, (float*)d_out);
}

// Round 16
// 83.739 us; speedup vs baseline: 1.0703x; 1.0703x over previous
//
#include <hip/hip_runtime.h>
#include <cstddef>

using bf16x8  = __attribute__((ext_vector_type(8))) short;
using short4v = __attribute__((ext_vector_type(4))) short;
using f32x4   = __attribute__((ext_vector_type(4))) float;
using ushort8 = __attribute__((ext_vector_type(8))) unsigned short;

#define GLL16(gp, lp) __builtin_amdgcn_global_load_lds( \
    (const __attribute__((address_space(1))) unsigned int*)(const void*)(gp), \
    (__attribute__((address_space(3))) unsigned int*)(void*)(lp), 16, 0, 0)

__device__ __forceinline__ float exp2_f(float x){ float r; asm("v_exp_f32 %0, %1" : "=v"(r) : "v"(x)); return r; }
__device__ __forceinline__ float rcp_f (float x){ float r; asm("v_rcp_f32 %0, %1" : "=v"(r) : "v"(x)); return r; }
__device__ __forceinline__ unsigned pk2(float lo, float hi){
  unsigned r; asm("v_cvt_pk_bf16_f32 %0, %1, %2" : "=v"(r) : "v"(lo), "v"(hi)); return r;
}
__device__ __forceinline__ unsigned short f2bf(float f){
  unsigned int u = __float_as_uint(f);
  u = u + 0x7FFFu + ((u >> 16) & 1u);
  return (unsigned short)(u >> 16);
}
__device__ __forceinline__ float bf2f(unsigned short s){
  return __uint_as_float(((unsigned int)s) << 16);
}

// 4-way merged reciprocal sum: a += sum_i vv_i/(1+ek_i*eq_i), ONE rcp per 4.
// D=(d0d1)(d2d3); N=(v0d1+v1d0)p23+(v2d3+v3d2)p01. d<=~200 -> D<=1.6e9, safe.
#define QUAD(E, k0v,k1v,k2v,k3v, w0v,w1v,w2v,w3v, a) { \
  const float d0 = fmaf((k0v), (E).x, 1.f); \
  const float d1 = fmaf((k1v), (E).y, 1.f); \
  const float d2 = fmaf((k2v), (E).z, 1.f); \
  const float d3 = fmaf((k3v), (E).w, 1.f); \
  const float p01 = d0 * d1, p23 = d2 * d3; \
  const float n01 = fmaf((w1v), d0, (w0v) * d1); \
  const float n23 = fmaf((w3v), d2, (w2v) * d3); \
  (a) = fmaf(fmaf(n01, p23, n23 * p01), rcp_f(p01 * p23), (a)); }

// problem sizes: B=8 Q=16 KV=2048 NQ=NK=NV=H=512
#define KEYS_N   8388608
#define QG_BLOCKS 16              // qgemm blocks FIRST (start at t=0, hide under convert)
#define CONV_BLOCKS 4224          // 4096 keys + 128 wk
#define SCALE_2LOG2E 2.885390081777927f   // 2*log2(e): exp2(x*S) = exp(2x)

// workspace layout (bytes); total = 22,806,528
#define OFF_KEYS_BF   0u          // 16384x512 bf16
#define OFF_WK_BF     16777216u   // 512x512 bf16
#define OFF_EQB       17301504u   // 128x512 f32: exp2(S*q_part)
#define OFF_EPART     17563648u   // 4 x [8*2048*16] f32 partial logits
#define OFF_SC        21757952u   // 8x2048x16 f32 scores

// ---------------- K1: q-GEMM (blocks 0..15) ∥ convert (blocks 16..4239) ---
__global__ __launch_bounds__(256) void k_convert(
    const float* __restrict__ keys, const float* __restrict__ W,
    const float* __restrict__ query,
    unsigned short* __restrict__ keys_bf, unsigned short* __restrict__ wk_bf,
    float* __restrict__ eqb)
{
  __shared__ short qg[128*32 + 32*32];     // 10 KB (qgemm branch only)
  if (blockIdx.x < QG_BLOCKS) {
    const int n0 = blockIdx.x * 32;
    const int tid = threadIdx.x;
    const int l = tid & 63, w = tid >> 6;
    short* A  = qg;                 // [128][32] swizzled
    short* Bs = qg + 4096;          // [32][32] swizzled
    const int sub = tid >> 3;       // 0..31
    const int c4  = (tid & 7) * 4;  // col within 32
    const int wm = w & 1, wn = w >> 1;
    const int fr = l & 15, fg = l >> 4;

    f32x4 acc[4];
    #pragma unroll
    for (int i = 0; i < 4; ++i) acc[i] = (f32x4){0.f,0.f,0.f,0.f};

    float4 a4[4], b4, a4n[4], b4n;
    #pragma unroll
    for (int m = 0; m < 4; ++m)
      a4[m] = *(const float4*)(query + (size_t)(m * 32 + sub) * 512 + c4);
    b4 = *(const float4*)(W + (size_t)(n0 + sub) * 1024 + c4);

    for (int kt = 0; kt < 16; ++kt) {
      if (kt < 15) {                 // issue next-kt loads early (overlap)
        const int k0 = (kt + 1) * 32;
        #pragma unroll
        for (int m = 0; m < 4; ++m)
          a4n[m] = *(const float4*)(query + (size_t)(m * 32 + sub) * 512 + k0 + c4);
        b4n = *(const float4*)(W + (size_t)(n0 + sub) * 1024 + k0 + c4);
      }
      __syncthreads();              // prior mfma reads done before overwrite
      #pragma unroll
      for (int m = 0; m < 4; ++m) {
        const int row = m * 32 + sub;
        const int o = row * 32 + (((c4 >> 3) ^ ((row >> 1) & 3)) << 3) + (c4 & 7);
        *(uint2*)&A[o] = make_uint2(pk2(a4[m].x, a4[m].y), pk2(a4[m].z, a4[m].w));
      }
      {
        const int o = sub * 32 + (((c4 >> 3) ^ ((sub >> 1) & 3)) << 3) + (c4 & 7);
        *(uint2*)&Bs[o] = make_uint2(pk2(b4.x, b4.y), pk2(b4.z, b4.w));
      }
      __syncthreads();
      bf16x8 af[4], bfv;
      #pragma unroll
      for (int i = 0; i < 4; ++i) {
        const int ar = wm*64 + i*16 + fr;
        af[i] = *(const bf16x8*)&A[ar*32 + ((fg ^ ((ar>>1)&3)) << 3)];
      }
      const int br = wn*16 + fr;
      bfv = *(const bf16x8*)&Bs[br*32 + ((fg ^ ((br>>1)&3)) << 3)];
      #pragma unroll
      for (int i = 0; i < 4; ++i)
        acc[i] = __builtin_amdgcn_mfma_f32_16x16x32_bf16(af[i], bfv, acc[i], 0, 0, 0);
      if (kt < 15) {
        #pragma unroll
        for (int m = 0; m < 4; ++m) a4[m] = a4n[m];
        b4 = b4n;
      }
    }
    const int gh = n0 + wn*16 + fr;
    #pragma unroll
    for (int i = 0; i < 4; ++i)
      #pragma unroll
      for (int r = 0; r < 4; ++r) {
        const int gm = wm*64 + i*16 + fg*4 + r;
        eqb[gm * 512 + gh] = exp2_f(acc[i][r] * SCALE_2LOG2E);
      }
    return;
  }
  // ---- convert path
  int idx = ((blockIdx.x - QG_BLOCKS) * 256 + threadIdx.x) * 8;
  const float* src;
  unsigned short* dst;
  if (idx < KEYS_N) { src = keys + idx; dst = keys_bf + idx; }
  else {
    int e = idx - KEYS_N;                    // wk[h][c]
    src = W + (size_t)(e >> 9) * 1024 + 512 + (e & 511);
    dst = wk_bf + e;
  }
  float4 a = *(const float4*)src;
  float4 b = *(const float4*)(src + 4);
  ushort8 o;
  o[0]=f2bf(a.x); o[1]=f2bf(a.y); o[2]=f2bf(a.z); o[3]=f2bf(a.w);
  o[4]=f2bf(b.x); o[5]=f2bf(b.y); o[6]=f2bf(b.z); o[7]=f2bf(b.w);
  *(ushort8*)dst = o;
}

// ---------------- K2: FUSED k-GEMM + energy (r12 base + 4-way rcp merge) --
struct FusedSM {
  union {
    struct { short A[2][8192]; short B[2][8192]; } g;  // 64 KB
    unsigned short ekbf[128 * 128];                    // 32 KB
  } u;
  float eqs[16 * 128];                                 // 8 KB
};

__global__ __launch_bounds__(256, 2) void k_fused(
    const unsigned short* __restrict__ keys_bf, const unsigned short* __restrict__ wk_bf,
    const float* __restrict__ w_bias, const float* __restrict__ eqb,
    const float* __restrict__ vw, float* __restrict__ e_part)
{
  __shared__ FusedSM sm;
  const int tid = threadIdx.x;
  const int l = tid & 63, w = tid >> 6;
  const int by = blockIdx.x;              // 0..127 m-tile (128 k-rows)
  const int hc = blockIdx.y;              // 0..3 h-chunk
  const int h0 = hc * 128;
  const int b  = by >> 4;

  // stage eqs [16 q][128 h] (disjoint LDS region; 2 oldest vm-loads)
  {
    const int q = tid >> 4, c0 = (tid & 15) * 8;
    const float* src = eqb + (size_t)(b * 16 + q) * 512 + h0 + c0;
    *(float4*)&sm.eqs[q * 128 + c0]     = *(const float4*)src;
    *(float4*)&sm.eqs[q * 128 + c0 + 4] = *(const float4*)(src + 4);
  }

  const unsigned short* Aptr = keys_bf + (size_t)by * 128 * 512;
  const unsigned short* Bptr = wk_bf + (size_t)h0 * 512;

  const int srow = w * 32 + (l >> 3);
  const int scol = ((l & 7) ^ (l >> 3)) * 8;
  const int wm = w >> 1, wn = w & 1;
  const int fr = l & 15, fg = l >> 4;
  const int axk = fr & 7;

  f32x4 acc[4][4];
  #pragma unroll
  for (int i = 0; i < 4; ++i)
    #pragma unroll
    for (int j = 0; j < 4; ++j) acc[i][j] = (f32x4){0.f,0.f,0.f,0.f};

  auto stage = [&](int buf, int kt) {
    const int k0 = kt * 64;
    #pragma unroll
    for (int r = 0; r < 4; ++r) {
      GLL16(Aptr + (srow + r * 8) * 512 + k0 + scol, &sm.u.g.A[buf][w * 2048 + r * 512]);
      GLL16(Bptr + (srow + r * 8) * 512 + k0 + scol, &sm.u.g.B[buf][w * 2048 + r * 512]);
    }
  };
  auto compute = [&](int buf) {
    #pragma unroll
    for (int ks = 0; ks < 2; ++ks) {
      bf16x8 af[4], bfv[4];
      #pragma unroll
      for (int i = 0; i < 4; ++i) {
        af[i]  = *(const bf16x8*)&sm.u.g.A[buf][(wm*64 + i*16 + fr) * 64 + ((ks*4 + fg) ^ axk) * 8];
        bfv[i] = *(const bf16x8*)&sm.u.g.B[buf][(wn*64 + i*16 + fr) * 64 + ((ks*4 + fg) ^ axk) * 8];
      }
      #pragma unroll
      for (int i = 0; i < 4; ++i)
        #pragma unroll
        for (int j = 0; j < 4; ++j)
          acc[i][j] = __builtin_amdgcn_mfma_f32_16x16x32_bf16(af[i], bfv[j], acc[i][j], 0, 0, 0);
    }
  };

  stage(0, 0);
  #pragma unroll 1
  for (int kt = 0; kt < 8; ++kt) {
    if (kt < 7) {
      stage((kt + 1) & 1, kt + 1);     // prefetch stays in flight across barrier
      asm volatile("s_waitcnt vmcnt(8)" ::: "memory");
    } else {
      asm volatile("s_waitcnt vmcnt(0)" ::: "memory");
    }
    __builtin_amdgcn_sched_barrier(0);
    __builtin_amdgcn_s_barrier();        // buf[kt&1] staged for ALL waves
    __builtin_amdgcn_sched_barrier(0);
    compute(kt & 1);
    asm volatile("s_waitcnt lgkmcnt(0)" ::: "memory");
    __builtin_amdgcn_sched_barrier(0);
    __builtin_amdgcn_s_barrier();        // all reads of buf[kt&1] done
    __builtin_amdgcn_sched_barrier(0);
  }

  // all waves: acc -> ekbf (bf16), swizzled chunk' = (col>>3) ^ (row&15)
  #pragma unroll
  for (int j = 0; j < 4; ++j) {
    const int col = wn*64 + j*16 + fr;
    const float bias = w_bias[h0 + col];
    const int chunk = col >> 3, coff = col & 7;
    #pragma unroll
    for (int i = 0; i < 4; ++i)
      #pragma unroll
      for (int r = 0; r < 4; ++r) {
        const int row = wm*64 + i*16 + fg*4 + r;       // row&15 = fg*4+r
        const float ev = exp2_f((acc[i][j][r] + bias) * SCALE_2LOG2E);
        sm.u.ekbf[row * 128 + ((chunk ^ (fg*4 + r)) << 3) + coff] = f2bf(ev);
      }
  }
  // v weights (pre-scaled by -2); lane owns h {s*32+g*4+u, s*32+16+g*4+u}
  const int g = l & 3, kl = l >> 2;
  float vv[32];
  #pragma unroll
  for (int s = 0; s < 4; ++s) {
    const float4 a0 = *(const float4*)(vw + h0 + s*32 + g*4);
    const float4 a1 = *(const float4*)(vw + h0 + s*32 + 16 + g*4);
    vv[s*8+0]=-2.f*a0.x; vv[s*8+1]=-2.f*a0.y; vv[s*8+2]=-2.f*a0.z; vv[s*8+3]=-2.f*a0.w;
    vv[s*8+4]=-2.f*a1.x; vv[s*8+5]=-2.f*a1.y; vv[s*8+6]=-2.f*a1.z; vv[s*8+7]=-2.f*a1.w;
  }
  __syncthreads();

  // energy: wave w owns rows {w*32+kl, w*32+16+kl}; one eqs pass serves both.
  // Per (q, s): 4 QUADs (2 rows x {E0,E1}), each 13 VALU + 1 rcp for 4 terms.
  {
    const int lr0 = w * 32 + kl;                 // lr0&15 = kl
    const int lr1 = lr0 + 16;                    // lr1&15 = kl (same ck)
    float ek0[32], ek1[32];
    #pragma unroll
    for (int s = 0; s < 4; ++s)
      #pragma unroll
      for (int hf = 0; hf < 2; ++hf) {
        const int ck = (4*s + 2*hf + (g >> 1)) ^ kl;
        const short4v v40 = *(const short4v*)&sm.u.ekbf[lr0 * 128 + (ck << 3) + (g & 1) * 4];
        const short4v v41 = *(const short4v*)&sm.u.ekbf[lr1 * 128 + (ck << 3) + (g & 1) * 4];
        #pragma unroll
        for (int u = 0; u < 4; ++u) {
          ek0[s*8 + hf*4 + u] = bf2f((unsigned short)v40[u]);
          ek1[s*8 + hf*4 + u] = bf2f((unsigned short)v41[u]);
        }
      }
    const size_t ep0 = (size_t)hc * 262144 + ((size_t)(by * 128 + lr0)) * 16;
    const size_t ep1 = (size_t)hc * 262144 + ((size_t)(by * 128 + lr1)) * 16;
    #pragma unroll 4
    for (int q = 0; q < 16; ++q) {
      float a00 = 0.f, a01 = 0.f, a10 = 0.f, a11 = 0.f;
      #pragma unroll
      for (int s = 0; s < 4; ++s) {
        const float* er = &sm.eqs[q * 128 + s * 32 + g * 4];
        const float4 E0 = *(const float4*)er;
        const float4 E1 = *(const float4*)(er + 16);
        QUAD(E0, ek0[s*8+0],ek0[s*8+1],ek0[s*8+2],ek0[s*8+3],
                 vv[s*8+0],vv[s*8+1],vv[s*8+2],vv[s*8+3], a00);
        QUAD(E1, ek0[s*8+4],ek0[s*8+5],ek0[s*8+6],ek0[s*8+7],
                 vv[s*8+4],vv[s*8+5],vv[s*8+6],vv[s*8+7], a01);
        QUAD(E0, ek1[s*8+0],ek1[s*8+1],ek1[s*8+2],ek1[s*8+3],
                 vv[s*8+0],vv[s*8+1],vv[s*8+2],vv[s*8+3], a10);
        QUAD(E1, ek1[s*8+4],ek1[s*8+5],ek1[s*8+6],ek1[s*8+7],
                 vv[s*8+4],vv[s*8+5],vv[s*8+6],vv[s*8+7], a11);
      }
      float r0 = a00 + a01;
      r0 += __shfl_xor(r0, 1, 64);
      r0 += __shfl_xor(r0, 2, 64);
      float r1 = a10 + a11;
      r1 += __shfl_xor(r1, 1, 64);
      r1 += __shfl_xor(r1, 2, 64);
      if (g == 0) { e_part[ep0 + q] = r0; e_part[ep1 + q] = r1; }
    }
  }
}

// ---------------- K3: softmax over k: sum 4 partials, normalize -----------
__global__ __launch_bounds__(256) void k_softmax(
    const float* __restrict__ e_part, float* __restrict__ sc)
{
  const int b = blockIdx.x >> 4, q = blockIdx.x & 15;
  const int base = b * 32768 + q;           // stride 16 over k
  const int tid = threadIdx.x;
  __shared__ float redm[4], reds[4];

  float vals[8];
  float mx = -1e30f;
  #pragma unroll
  for (int i = 0; i < 8; ++i) {
    const int x = base + (tid + i * 256) * 16;
    vals[i] = (e_part[x] + e_part[x + 262144]) + (e_part[x + 524288] + e_part[x + 786432]);
    mx = fmaxf(mx, vals[i]);
  }
  #pragma unroll
  for (int msk = 1; msk < 64; msk <<= 1) mx = fmaxf(mx, __shfl_xor(mx, msk, 64));
  if ((tid & 63) == 0) redm[tid >> 6] = mx;
  __syncthreads();
  mx = fmaxf(fmaxf(redm[0], redm[1]), fmaxf(redm[2], redm[3]));

  float ex[8], sum = 0.f;
  #pragma unroll
  for (int i = 0; i < 8; ++i) { ex[i] = __expf(vals[i] - mx); sum += ex[i]; }
  #pragma unroll
  for (int msk = 1; msk < 64; msk <<= 1) sum += __shfl_xor(sum, msk, 64);
  if ((tid & 63) == 0) reds[tid >> 6] = sum;
  __syncthreads();
  sum = reds[0] + reds[1] + reds[2] + reds[3];
  const float r = 1.f / sum;
  #pragma unroll
  for (int i = 0; i < 8; ++i) sc[base + (tid + i * 256) * 16] = ex[i] * r;
}

// ---------------- K4: single-pass PV -> out, 256 blocks x 512 thr ---------
__global__ __launch_bounds__(512) void k_pv(
    const float* __restrict__ values, const float* __restrict__ sc,
    float* __restrict__ out)
{
  __shared__ float lds[128 * 20];            // 10 KB (stride-20: 2-way max)
  const int tid = threadIdx.x;
  const int nc = blockIdx.x & 31, b = blockIdx.x >> 5;
  const int n = tid & 15, kg = tid >> 4;     // 32 kg x 16 n
  const int l = tid & 63, w = tid >> 6;      // 8 waves
  const int n0 = nc * 16;

  float acc[16];
  #pragma unroll
  for (int q = 0; q < 16; ++q) acc[q] = 0.f;

  for (int kc = 0; kc < 16; ++kc) {
    __syncthreads();
    {
      const float* ssrc = sc + (size_t)(b * 2048 + kc * 128) * 16;
      const int row = tid >> 2, c4 = (tid & 3) * 4;
      *(float4*)&lds[row * 20 + c4] = *(const float4*)&ssrc[row * 16 + c4];
    }
    __syncthreads();
    const float* vb = values + ((size_t)(b * 2048 + kc * 128 + kg * 4)) * 512 + n0 + n;
    #pragma unroll
    for (int k2 = 0; k2 < 4; ++k2) {
      const float v = vb[(size_t)k2 * 512];
      const float* sr = &lds[(kg * 4 + k2) * 20];
      #pragma unroll
      for (int qq = 0; qq < 4; ++qq) {
        const float4 s4 = *(const float4*)&sr[qq * 4];
        acc[qq*4+0] = fmaf(v, s4.x, acc[qq*4+0]);
        acc[qq*4+1] = fmaf(v, s4.y, acc[qq*4+1]);
        acc[qq*4+2] = fmaf(v, s4.z, acc[qq*4+2]);
        acc[qq*4+3] = fmaf(v, s4.w, acc[qq*4+3]);
      }
    }
  }
  // within-wave reduce (lanes l, l^16, l^32 share n)
  #pragma unroll
  for (int q = 0; q < 16; ++q) {
    acc[q] += __shfl_xor(acc[q], 16, 64);
    acc[q] += __shfl_xor(acc[q], 32, 64);
  }
  __syncthreads();
  if (l < 16) {
    #pragma unroll
    for (int q = 0; q < 16; ++q) lds[w * 256 + q * 16 + l] = acc[q];
  }
  __syncthreads();
  if (tid < 256) {
    const int q = tid >> 4, nn = tid & 15;
    float s = 0.f;
    #pragma unroll
    for (int w2 = 0; w2 < 8; ++w2) s += lds[w2 * 256 + q * 16 + nn];
    out[((size_t)(b * 16 + q)) * 512 + n0 + nn] = s;
  }
}

extern "C" void kernel_launch(void* const* d_in, const int* in_sizes, int n_in,
                              void* d_out, int out_size, void* d_ws, size_t ws_size,
                              hipStream_t stream)
{
  const float* query  = (const float*)d_in[0];
  const float* keys   = (const float*)d_in[1];
  const float* values = (const float*)d_in[2];
  const float* W      = (const float*)d_in[3];
  const float* w_bias = (const float*)d_in[4];
  const float* vw     = (const float*)d_in[5];
  // d_in[6] (v_bias) + sum_h v_h are (k)-constant logit shifts -> softmax-invariant.

  char* ws = (char*)d_ws;
  unsigned short* keys_bf = (unsigned short*)(ws + OFF_KEYS_BF);
  unsigned short* wk_bf   = (unsigned short*)(ws + OFF_WK_BF);
  float* eqb    = (float*)(ws + OFF_EQB);
  float* e_part = (float*)(ws + OFF_EPART);
  float* sc     = (float*)(ws + OFF_SC);

  hipLaunchKernelGGL(k_convert, dim3(QG_BLOCKS + CONV_BLOCKS), dim3(256), 0, stream,
                     keys, W, query, keys_bf, wk_bf, eqb);
  hipLaunchKernelGGL(k_fused, dim3(128, 4), dim3(256), 0, stream,
                     keys_bf, wk_bf, w_bias, eqb, vw, e_part);
  hipLaunchKernelGGL(k_softmax, dim3(128), dim3(256), 0, stream, e_part, sc);
  hipLaunchKernelGGL(k_pv, dim3(256), dim3(512), 0, stream, values, sc, (float*)d_out);
}

// Round 17
// 82.880 us; speedup vs baseline: 1.0814x; 1.0104x over previous
//
#include <hip/hip_runtime.h>
#include <cstddef>

using bf16x8  = __attribute__((ext_vector_type(8))) short;
using short4v = __attribute__((ext_vector_type(4))) short;
using f32x4   = __attribute__((ext_vector_type(4))) float;
using ushort8 = __attribute__((ext_vector_type(8))) unsigned short;

#define GLL16(gp, lp) __builtin_amdgcn_global_load_lds( \
    (const __attribute__((address_space(1))) unsigned int*)(const void*)(gp), \
    (__attribute__((address_space(3))) unsigned int*)(void*)(lp), 16, 0, 0)

__device__ __forceinline__ float exp2_f(float x){ float r; asm("v_exp_f32 %0, %1" : "=v"(r) : "v"(x)); return r; }
__device__ __forceinline__ float rcp_f (float x){ float r; asm("v_rcp_f32 %0, %1" : "=v"(r) : "v"(x)); return r; }
__device__ __forceinline__ unsigned pk2(float lo, float hi){
  unsigned r; asm("v_cvt_pk_bf16_f32 %0, %1, %2" : "=v"(r) : "v"(lo), "v"(hi)); return r;
}
__device__ __forceinline__ unsigned short f2bf(float f){
  unsigned int u = __float_as_uint(f);
  u = u + 0x7FFFu + ((u >> 16) & 1u);
  return (unsigned short)(u >> 16);
}
__device__ __forceinline__ float bf2f(unsigned short s){
  return __uint_as_float(((unsigned int)s) << 16);
}

// 4-way merged reciprocal sum: a += sum_i vv_i/(1+ek_i*eq_i), ONE rcp per 4.
#define QUAD(E, k0v,k1v,k2v,k3v, w0v,w1v,w2v,w3v, a) { \
  const float d0 = fmaf((k0v), (E).x, 1.f); \
  const float d1 = fmaf((k1v), (E).y, 1.f); \
  const float d2 = fmaf((k2v), (E).z, 1.f); \
  const float d3 = fmaf((k3v), (E).w, 1.f); \
  const float p01 = d0 * d1, p23 = d2 * d3; \
  const float n01 = fmaf((w1v), d0, (w0v) * d1); \
  const float n23 = fmaf((w3v), d2, (w2v) * d3); \
  (a) = fmaf(fmaf(n01, p23, n23 * p01), rcp_f(p01 * p23), (a)); }

// problem sizes: B=8 Q=16 KV=2048 NQ=NK=NV=H=512
#define QG_BLOCKS 16              // qgemm blocks (reads query/W f32 directly)
#define WK_BLOCKS 128             // wk f32->bf16 convert
#define SCALE_2LOG2E 2.885390081777927f   // 2*log2(e): exp2(x*S) = exp(2x)

// workspace layout (bytes); total = 6,029,312 (keys_bf deleted!)
#define OFF_WK_BF     0u          // 512x512 bf16
#define OFF_EQB       524288u     // 128x512 f32: exp2(S*q_part)
#define OFF_EPART     786432u     // 4 x [8*2048*16] f32 partial logits
#define OFF_SC        4980736u    // 8x2048x16 f32 scores

// ---------------- K1: q-GEMM (blocks 0..15) ∥ wk convert (16..143) --------
__global__ __launch_bounds__(256) void k_convert(
    const float* __restrict__ W, const float* __restrict__ query,
    unsigned short* __restrict__ wk_bf, float* __restrict__ eqb)
{
  __shared__ short qg[128*32 + 32*32];     // 10 KB (qgemm branch only)
  if (blockIdx.x < QG_BLOCKS) {
    const int n0 = blockIdx.x * 32;
    const int tid = threadIdx.x;
    const int l = tid & 63, w = tid >> 6;
    short* A  = qg;                 // [128][32] swizzled
    short* Bs = qg + 4096;          // [32][32] swizzled
    const int sub = tid >> 3;       // 0..31
    const int c4  = (tid & 7) * 4;  // col within 32
    const int wm = w & 1, wn = w >> 1;
    const int fr = l & 15, fg = l >> 4;

    f32x4 acc[4];
    #pragma unroll
    for (int i = 0; i < 4; ++i) acc[i] = (f32x4){0.f,0.f,0.f,0.f};

    float4 a4[4], b4, a4n[4], b4n;
    #pragma unroll
    for (int m = 0; m < 4; ++m)
      a4[m] = *(const float4*)(query + (size_t)(m * 32 + sub) * 512 + c4);
    b4 = *(const float4*)(W + (size_t)(n0 + sub) * 1024 + c4);

    for (int kt = 0; kt < 16; ++kt) {
      if (kt < 15) {                 // issue next-kt loads early (overlap)
        const int k0 = (kt + 1) * 32;
        #pragma unroll
        for (int m = 0; m < 4; ++m)
          a4n[m] = *(const float4*)(query + (size_t)(m * 32 + sub) * 512 + k0 + c4);
        b4n = *(const float4*)(W + (size_t)(n0 + sub) * 1024 + k0 + c4);
      }
      __syncthreads();              // prior mfma reads done before overwrite
      #pragma unroll
      for (int m = 0; m < 4; ++m) {
        const int row = m * 32 + sub;
        const int o = row * 32 + (((c4 >> 3) ^ ((row >> 1) & 3)) << 3) + (c4 & 7);
        *(uint2*)&A[o] = make_uint2(pk2(a4[m].x, a4[m].y), pk2(a4[m].z, a4[m].w));
      }
      {
        const int o = sub * 32 + (((c4 >> 3) ^ ((sub >> 1) & 3)) << 3) + (c4 & 7);
        *(uint2*)&Bs[o] = make_uint2(pk2(b4.x, b4.y), pk2(b4.z, b4.w));
      }
      __syncthreads();
      bf16x8 af[4], bfv;
      #pragma unroll
      for (int i = 0; i < 4; ++i) {
        const int ar = wm*64 + i*16 + fr;
        af[i] = *(const bf16x8*)&A[ar*32 + ((fg ^ ((ar>>1)&3)) << 3)];
      }
      const int br = wn*16 + fr;
      bfv = *(const bf16x8*)&Bs[br*32 + ((fg ^ ((br>>1)&3)) << 3)];
      #pragma unroll
      for (int i = 0; i < 4; ++i)
        acc[i] = __builtin_amdgcn_mfma_f32_16x16x32_bf16(af[i], bfv, acc[i], 0, 0, 0);
      if (kt < 15) {
        #pragma unroll
        for (int m = 0; m < 4; ++m) a4[m] = a4n[m];
        b4 = b4n;
      }
    }
    const int gh = n0 + wn*16 + fr;
    #pragma unroll
    for (int i = 0; i < 4; ++i)
      #pragma unroll
      for (int r = 0; r < 4; ++r) {
        const int gm = wm*64 + i*16 + fg*4 + r;
        eqb[gm * 512 + gh] = exp2_f(acc[i][r] * SCALE_2LOG2E);
      }
    return;
  }
  // ---- wk convert path: 128 blocks x 2048 elems = 262144 exact
  int e = (blockIdx.x - QG_BLOCKS) * 2048 + threadIdx.x * 8;
  const float* src = W + (size_t)(e >> 9) * 1024 + 512 + (e & 511);
  float4 a = *(const float4*)src;
  float4 b = *(const float4*)(src + 4);
  ushort8 o;
  o[0]=f2bf(a.x); o[1]=f2bf(a.y); o[2]=f2bf(a.z); o[3]=f2bf(a.w);
  o[4]=f2bf(b.x); o[5]=f2bf(b.y); o[6]=f2bf(b.z); o[7]=f2bf(b.w);
  *(ushort8*)&wk_bf[e] = o;
}

// ---------------- K2: FUSED convert + k-GEMM + energy ---------------------
// A tile: keys f32 reg-staged (8 float4/thread), cvt_pk, swizzled ds_write
// (T14 issue-early/write-late; deletes the 50MB keys convert pass).
// B tile: GLL16 from wk_bf. Counted-vmcnt ledger:
//   pre-barrier: outstanding = [B(kt) 4][aload(kt+1) 8] -> vmcnt(8) drains B(kt)
//   post-compute: [aload(kt+1) 8][B(kt+1) 4] -> vmcnt(4) drains aloads
struct FusedSM {
  union {
    struct { short A[2][8192]; short B[2][8192]; } g;  // 64 KB
    unsigned short ekbf[128 * 128];                    // 32 KB
  } u;
  float eqs[16 * 128];                                 // 8 KB
};

__global__ __launch_bounds__(256, 2) void k_fused(
    const float* __restrict__ keys, const unsigned short* __restrict__ wk_bf,
    const float* __restrict__ w_bias, const float* __restrict__ eqb,
    const float* __restrict__ vw, float* __restrict__ e_part)
{
  __shared__ FusedSM sm;
  const int tid = threadIdx.x;
  const int l = tid & 63, w = tid >> 6;
  const int by = blockIdx.x;              // 0..127 m-tile (128 k-rows)
  const int hc = blockIdx.y;              // 0..3 h-chunk
  const int h0 = hc * 128;
  const int b  = by >> 4;

  // stage eqs [16 q][128 h]; drain so the vmcnt ledger below starts at 0
  {
    const int q = tid >> 4, c0 = (tid & 15) * 8;
    const float* src = eqb + (size_t)(b * 16 + q) * 512 + h0 + c0;
    *(float4*)&sm.eqs[q * 128 + c0]     = *(const float4*)src;
    *(float4*)&sm.eqs[q * 128 + c0 + 4] = *(const float4*)(src + 4);
  }
  asm volatile("s_waitcnt vmcnt(0)" ::: "memory");

  const float* Akeys = keys + (size_t)by * 128 * 512;
  const unsigned short* Bptr = wk_bf + (size_t)h0 * 512;

  const int srow = w * 32 + (l >> 3);
  const int scol = ((l & 7) ^ (l >> 3)) * 8;
  const int wm = w >> 1, wn = w & 1;
  const int fr = l & 15, fg = l >> 4;
  const int axk = fr & 7;

  f32x4 acc[4][4];
  #pragma unroll
  for (int i = 0; i < 4; ++i)
    #pragma unroll
    for (int j = 0; j < 4; ++j) acc[i][j] = (f32x4){0.f,0.f,0.f,0.f};

  float4 areg[8];
  auto aload = [&](int kt) {          // 8 float4 global loads (coalesced)
    const float* src = Akeys + kt * 64;
    #pragma unroll
    for (int m = 0; m < 8; ++m) {
      const int u = m * 256 + tid;    // float4 unit in 128x64 tile
      areg[m] = *(const float4*)(src + (size_t)(u >> 4) * 512 + (u & 15) * 4);
    }
  };
  auto awrite = [&](int buf) {        // cvt_pk + swizzled ds_write_b64
    #pragma unroll
    for (int m = 0; m < 8; ++m) {
      const int u = m * 256 + tid;
      const int row = u >> 4, c4 = u & 15;      // c4 = float4 index (0..15)
      const int o = row * 64 + (((c4 >> 1) ^ (row & 7)) << 3) + (c4 & 1) * 4;
      *(uint2*)&sm.u.g.A[buf][o] =
          make_uint2(pk2(areg[m].x, areg[m].y), pk2(areg[m].z, areg[m].w));
    }
  };
  auto bstage = [&](int buf, int kt) {  // 4 GLL16
    const int k0 = kt * 64;
    #pragma unroll
    for (int r = 0; r < 4; ++r)
      GLL16(Bptr + (srow + r * 8) * 512 + k0 + scol, &sm.u.g.B[buf][w * 2048 + r * 512]);
  };
  auto compute = [&](int buf) {
    #pragma unroll
    for (int ks = 0; ks < 2; ++ks) {
      bf16x8 af[4], bfv[4];
      #pragma unroll
      for (int i = 0; i < 4; ++i) {
        af[i]  = *(const bf16x8*)&sm.u.g.A[buf][(wm*64 + i*16 + fr) * 64 + ((ks*4 + fg) ^ axk) * 8];
        bfv[i] = *(const bf16x8*)&sm.u.g.B[buf][(wn*64 + i*16 + fr) * 64 + ((ks*4 + fg) ^ axk) * 8];
      }
      #pragma unroll
      for (int i = 0; i < 4; ++i)
        #pragma unroll
        for (int j = 0; j < 4; ++j)
          acc[i][j] = __builtin_amdgcn_mfma_f32_16x16x32_bf16(af[i], bfv[j], acc[i][j], 0, 0, 0);
    }
  };

  // prologue: tile 0 fully staged
  aload(0);
  asm volatile("s_waitcnt vmcnt(0)" ::: "memory");
  awrite(0);
  bstage(0, 0);

  #pragma unroll 1
  for (int kt = 0; kt < 8; ++kt) {
    if (kt < 7) {
      aload(kt + 1);                               // 8 loads in flight
      asm volatile("s_waitcnt vmcnt(8)" ::: "memory");   // B(kt) landed
    } else {
      asm volatile("s_waitcnt vmcnt(0)" ::: "memory");
    }
    asm volatile("s_waitcnt lgkmcnt(0)" ::: "memory");   // A(kt) ds_writes done
    __builtin_amdgcn_sched_barrier(0);
    __builtin_amdgcn_s_barrier();        // buf[kt&1] staged for ALL waves
    __builtin_amdgcn_sched_barrier(0);
    if (kt < 7) bstage((kt + 1) & 1, kt + 1);   // post-barrier: buf^1 readers done
    compute(kt & 1);
    if (kt < 7) {
      asm volatile("s_waitcnt vmcnt(4)" ::: "memory");   // aloads landed (B(kt+1) in flight)
      __builtin_amdgcn_sched_barrier(0);
      awrite((kt + 1) & 1);                              // buf^1 readers done at barrier
    }
  }
  asm volatile("s_waitcnt lgkmcnt(0)" ::: "memory");
  __builtin_amdgcn_sched_barrier(0);
  __builtin_amdgcn_s_barrier();          // all frag reads done before ekbf overwrite
  __builtin_amdgcn_sched_barrier(0);

  // all waves: acc -> ekbf (bf16), swizzled chunk' = (col>>3) ^ (row&15)
  #pragma unroll
  for (int j = 0; j < 4; ++j) {
    const int col = wn*64 + j*16 + fr;
    const float bias = w_bias[h0 + col];
    const int chunk = col >> 3, coff = col & 7;
    #pragma unroll
    for (int i = 0; i < 4; ++i)
      #pragma unroll
      for (int r = 0; r < 4; ++r) {
        const int row = wm*64 + i*16 + fg*4 + r;       // row&15 = fg*4+r
        const float ev = exp2_f((acc[i][j][r] + bias) * SCALE_2LOG2E);
        sm.u.ekbf[row * 128 + ((chunk ^ (fg*4 + r)) << 3) + coff] = f2bf(ev);
      }
  }
  // v weights (pre-scaled by -2); lane owns h {s*32+g*4+u, s*32+16+g*4+u}
  const int g = l & 3, kl = l >> 2;
  float vv[32];
  #pragma unroll
  for (int s = 0; s < 4; ++s) {
    const float4 a0 = *(const float4*)(vw + h0 + s*32 + g*4);
    const float4 a1 = *(const float4*)(vw + h0 + s*32 + 16 + g*4);
    vv[s*8+0]=-2.f*a0.x; vv[s*8+1]=-2.f*a0.y; vv[s*8+2]=-2.f*a0.z; vv[s*8+3]=-2.f*a0.w;
    vv[s*8+4]=-2.f*a1.x; vv[s*8+5]=-2.f*a1.y; vv[s*8+6]=-2.f*a1.z; vv[s*8+7]=-2.f*a1.w;
  }
  __syncthreads();

  // energy: wave w owns rows {w*32+kl, w*32+16+kl}; QUAD: 1 rcp per 4 terms
  {
    const int lr0 = w * 32 + kl;                 // lr0&15 = kl
    const int lr1 = lr0 + 16;                    // lr1&15 = kl (same ck)
    float ek0[32], ek1[32];
    #pragma unroll
    for (int s = 0; s < 4; ++s)
      #pragma unroll
      for (int hf = 0; hf < 2; ++hf) {
        const int ck = (4*s + 2*hf + (g >> 1)) ^ kl;
        const short4v v40 = *(const short4v*)&sm.u.ekbf[lr0 * 128 + (ck << 3) + (g & 1) * 4];
        const short4v v41 = *(const short4v*)&sm.u.ekbf[lr1 * 128 + (ck << 3) + (g & 1) * 4];
        #pragma unroll
        for (int u = 0; u < 4; ++u) {
          ek0[s*8 + hf*4 + u] = bf2f((unsigned short)v40[u]);
          ek1[s*8 + hf*4 + u] = bf2f((unsigned short)v41[u]);
        }
      }
    const size_t ep0 = (size_t)hc * 262144 + ((size_t)(by * 128 + lr0)) * 16;
    const size_t ep1 = (size_t)hc * 262144 + ((size_t)(by * 128 + lr1)) * 16;
    #pragma unroll 4
    for (int q = 0; q < 16; ++q) {
      float a00 = 0.f, a01 = 0.f, a10 = 0.f, a11 = 0.f;
      #pragma unroll
      for (int s = 0; s < 4; ++s) {
        const float* er = &sm.eqs[q * 128 + s * 32 + g * 4];
        const float4 E0 = *(const float4*)er;
        const float4 E1 = *(const float4*)(er + 16);
        QUAD(E0, ek0[s*8+0],ek0[s*8+1],ek0[s*8+2],ek0[s*8+3],
                 vv[s*8+0],vv[s*8+1],vv[s*8+2],vv[s*8+3], a00);
        QUAD(E1, ek0[s*8+4],ek0[s*8+5],ek0[s*8+6],ek0[s*8+7],
                 vv[s*8+4],vv[s*8+5],vv[s*8+6],vv[s*8+7], a01);
        QUAD(E0, ek1[s*8+0],ek1[s*8+1],ek1[s*8+2],ek1[s*8+3],
                 vv[s*8+0],vv[s*8+1],vv[s*8+2],vv[s*8+3], a10);
        QUAD(E1, ek1[s*8+4],ek1[s*8+5],ek1[s*8+6],ek1[s*8+7],
                 vv[s*8+4],vv[s*8+5],vv[s*8+6],vv[s*8+7], a11);
      }
      float r0 = a00 + a01;
      r0 += __shfl_xor(r0, 1, 64);
      r0 += __shfl_xor(r0, 2, 64);
      float r1 = a10 + a11;
      r1 += __shfl_xor(r1, 1, 64);
      r1 += __shfl_xor(r1, 2, 64);
      if (g == 0) { e_part[ep0 + q] = r0; e_part[ep1 + q] = r1; }
    }
  }
}

// ---------------- K3: softmax over k: sum 4 partials, normalize -----------
__global__ __launch_bounds__(256) void k_softmax(
    const float* __restrict__ e_part, float* __restrict__ sc)
{
  const int b = blockIdx.x >> 4, q = blockIdx.x & 15;
  const int base = b * 32768 + q;           // stride 16 over k
  const int tid = threadIdx.x;
  __shared__ float redm[4], reds[4];

  float vals[8];
  float mx = -1e30f;
  #pragma unroll
  for (int i = 0; i < 8; ++i) {
    const int x = base + (tid + i * 256) * 16;
    vals[i] = (e_part[x] + e_part[x + 262144]) + (e_part[x + 524288] + e_part[x + 786432]);
    mx = fmaxf(mx, vals[i]);
  }
  #pragma unroll
  for (int msk = 1; msk < 64; msk <<= 1) mx = fmaxf(mx, __shfl_xor(mx, msk, 64));
  if ((tid & 63) == 0) redm[tid >> 6] = mx;
  __syncthreads();
  mx = fmaxf(fmaxf(redm[0], redm[1]), fmaxf(redm[2], redm[3]));

  float ex[8], sum = 0.f;
  #pragma unroll
  for (int i = 0; i < 8; ++i) { ex[i] = __expf(vals[i] - mx); sum += ex[i]; }
  #pragma unroll
  for (int msk = 1; msk < 64; msk <<= 1) sum += __shfl_xor(sum, msk, 64);
  if ((tid & 63) == 0) reds[tid >> 6] = sum;
  __syncthreads();
  sum = reds[0] + reds[1] + reds[2] + reds[3];
  const float r = 1.f / sum;
  #pragma unroll
  for (int i = 0; i < 8; ++i) sc[base + (tid + i * 256) * 16] = ex[i] * r;
}

// ---------------- K4: single-pass PV -> out, 256 blocks x 512 thr ---------
__global__ __launch_bounds__(512) void k_pv(
    const float* __restrict__ values, const float* __restrict__ sc,
    float* __restrict__ out)
{
  __shared__ float lds[128 * 20];            // 10 KB (stride-20: 2-way max)
  const int tid = threadIdx.x;
  const int nc = blockIdx.x & 31, b = blockIdx.x >> 5;
  const int n = tid & 15, kg = tid >> 4;     // 32 kg x 16 n
  const int l = tid & 63, w = tid >> 6;      // 8 waves
  const int n0 = nc * 16;

  float acc[16];
  #pragma unroll
  for (int q = 0; q < 16; ++q) acc[q] = 0.f;

  for (int kc = 0; kc < 16; ++kc) {
    __syncthreads();
    {
      const float* ssrc = sc + (size_t)(b * 2048 + kc * 128) * 16;
      const int row = tid >> 2, c4 = (tid & 3) * 4;
      *(float4*)&lds[row * 20 + c4] = *(const float4*)&ssrc[row * 16 + c4];
    }
    __syncthreads();
    const float* vb = values + ((size_t)(b * 2048 + kc * 128 + kg * 4)) * 512 + n0 + n;
    #pragma unroll
    for (int k2 = 0; k2 < 4; ++k2) {
      const float v = vb[(size_t)k2 * 512];
      const float* sr = &lds[(kg * 4 + k2) * 20];
      #pragma unroll
      for (int qq = 0; qq < 4; ++qq) {
        const float4 s4 = *(const float4*)&sr[qq * 4];
        acc[qq*4+0] = fmaf(v, s4.x, acc[qq*4+0]);
        acc[qq*4+1] = fmaf(v, s4.y, acc[qq*4+1]);
        acc[qq*4+2] = fmaf(v, s4.z, acc[qq*4+2]);
        acc[qq*4+3] = fmaf(v, s4.w, acc[qq*4+3]);
      }
    }
  }
  // within-wave reduce (lanes l, l^16, l^32 share n)
  #pragma unroll
  for (int q = 0; q < 16; ++q) {
    acc[q] += __shfl_xor(acc[q], 16, 64);
    acc[q] += __shfl_xor(acc[q], 32, 64);
  }
  __syncthreads();
  if (l < 16) {
    #pragma unroll
    for (int q = 0; q < 16; ++q) lds[w * 256 + q * 16 + l] = acc[q];
  }
  __syncthreads();
  if (tid < 256) {
    const int q = tid >> 4, nn = tid & 15;
    float s = 0.f;
    #pragma unroll
    for (int w2 = 0; w2 < 8; ++w2) s += lds[w2 * 256 + q * 16 + nn];
    out[((size_t)(b * 16 + q)) * 512 + n0 + nn] = s;
  }
}

extern "C" void kernel_launch(void* const* d_in, const int* in_sizes, int n_in,
                              void* d_out, int out_size, void* d_ws, size_t ws_size,
                              hipStream_t stream)
{
  const float* query  = (const float*)d_in[0];
  const float* keys   = (const float*)d_in[1];
  const float* values = (const float*)d_in[2];
  const float* W      = (const float*)d_in[3];
  const float* w_bias = (const float*)d_in[4];
  const float* vw     = (const float*)d_in[5];
  // d_in[6] (v_bias) + sum_h v_h are (k)-constant logit shifts -> softmax-invariant.

  char* ws = (char*)d_ws;
  unsigned short* wk_bf = (unsigned short*)(ws + OFF_WK_BF);
  float* eqb    = (float*)(ws + OFF_EQB);
  float* e_part = (float*)(ws + OFF_EPART);
  float* sc     = (float*)(ws + OFF_SC);

  hipLaunchKernelGGL(k_convert, dim3(QG_BLOCKS + WK_BLOCKS), dim3(256), 0, stream,
                     W, query, wk_bf, eqb);
  hipLaunchKernelGGL(k_fused, dim3(128, 4), dim3(256), 0, stream,
                     keys, wk_bf, w_bias, eqb, vw, e_part);
  hipLaunchKernelGGL(k_softmax, dim3(128), dim3(256), 0, stream, e_part, sc);
  hipLaunchKernelGGL(k_pv, dim3(256), dim3(512), 0, stream, values, sc, (float*)d_out);
}